// Round 4
// baseline (82.813 us; speedup 1.0000x reference)
//
#include <hip/hip_runtime.h>

#define BN 512   // batch
#define DD 512   // feature dim
#define LL 24    // label dim
#define NB 512   // main kernel: one block per row
#define NT 512   // threads per block (8 waves)

// ws layout (float words): [0, 1024) per-block slots: block b -> {sum(f32), cnt(u32)}
// Slots are written unconditionally by every block (poison-safe, no init, no atomics).

// ---------------- main kernel: one row per block, negative-sparse ------------
// Phase A: all 512 label masks built redundantly per block (48 KB, L2-hot).
// Phase B: block-uniform activity check: row i contributes iff it has >=1
//          negative j ((mi & mj)==0). P(neg pair) = (3/4)^24 ~ 0.001 ->
//          ~60% of blocks exit here having read only the 48 KB label block.
// Phase C (active only): compute distance row d_i[0..511] directly:
//          wave w owns j in [64w, 64w+64), 2-way interleaved for ILP; per j
//          the wave reads s_j fully coalesced (2 KB), diff-squares against
//          s_i held in registers (8 floats/lane), butterfly-reduces, sqrt.
//          Exact 0 on the diagonal (s_i - s_i), matching the reference zmask.
// Phase D: wave 0 runs the R2-verified ballot triplet loop from LDS.
__global__ __launch_bounds__(NT) void row_kernel(
    const float* __restrict__ S, const int* __restrict__ labels,
    float* __restrict__ slots)
{
    __shared__ unsigned mask_lds[BN];
    __shared__ float    d_lds[BN];
    __shared__ int      anyneg_s;

    const int t    = threadIdx.x;
    const int lane = t & 63;
    const int w    = t >> 6;
    const int i    = blockIdx.x;

    if (t == 0) anyneg_s = 0;

    // ---- phase A: mask for row t (24 ints = 6 x int4, 96 B, 16B-aligned) ----
    {
        const int4* lab4 = (const int4*)(labels + (size_t)t * LL);
        unsigned m = 0;
#pragma unroll
        for (int v = 0; v < 6; v++) {
            int4 x = lab4[v];
            m |= (x.x ? 1u : 0u) << (4 * v)
               | (x.y ? 1u : 0u) << (4 * v + 1)
               | (x.z ? 1u : 0u) << (4 * v + 2)
               | (x.w ? 1u : 0u) << (4 * v + 3);
        }
        mask_lds[t] = m;
    }
    __syncthreads();                       // masks + anyneg_s init visible

    const unsigned mi = mask_lds[i];
    if ((mi & mask_lds[t]) == 0u) anyneg_s = 1;   // benign same-value race
    __syncthreads();                       // activity flag final (block-uniform)

    float sum = 0.f; unsigned cnt = 0u;

    if (anyneg_s) {
        // ---- phase C: distance row sweep ----
        const float* si_p = S + (size_t)i * DD + 8 * lane;
        const float4 si0 = *(const float4*)si_p;
        const float4 si1 = *(const float4*)(si_p + 4);

        const int jbase = w << 6;
        for (int jj = 0; jj < 32; jj++) {
            const int jA = jbase + jj, jB = jA + 32;
            const float* pa = S + (size_t)jA * DD + 8 * lane;
            const float* pb = S + (size_t)jB * DD + 8 * lane;
            const float4 a0 = *(const float4*)pa, a1 = *(const float4*)(pa + 4);
            const float4 b0 = *(const float4*)pb, b1 = *(const float4*)(pb + 4);

            float dA, dB;
            {
                float v;
                v = a0.x - si0.x; dA  = v * v;   v = b0.x - si0.x; dB  = v * v;
                v = a0.y - si0.y; dA += v * v;   v = b0.y - si0.y; dB += v * v;
                v = a0.z - si0.z; dA += v * v;   v = b0.z - si0.z; dB += v * v;
                v = a0.w - si0.w; dA += v * v;   v = b0.w - si0.w; dB += v * v;
                v = a1.x - si1.x; dA += v * v;   v = b1.x - si1.x; dB += v * v;
                v = a1.y - si1.y; dA += v * v;   v = b1.y - si1.y; dB += v * v;
                v = a1.z - si1.z; dA += v * v;   v = b1.z - si1.z; dB += v * v;
                v = a1.w - si1.w; dA += v * v;   v = b1.w - si1.w; dB += v * v;
            }
#pragma unroll
            for (int off = 1; off < 64; off <<= 1) {     // full butterfly
                dA += __shfl_xor(dA, off);
                dB += __shfl_xor(dB, off);
            }
            if (lane == 0) {
                d_lds[jA] = sqrtf(fmaxf(dA, 0.f));
                d_lds[jB] = sqrtf(fmaxf(dB, 0.f));
            }
        }
        __syncthreads();                   // d row complete

        // ---- phase D: triplet loop (wave 0 only; R2-verified structure) ----
        if (w == 0) {
            unsigned long long pb[8]; float dv[8];
#pragma unroll
            for (int c = 0; c < 8; c++) {
                pb[c] = __ballot((mi & mask_lds[c * 64 + lane]) != 0u);
                dv[c] = d_lds[c * 64 + lane];
            }
#pragma unroll
            for (int c = 0; c < 8; c++) {
                unsigned long long nb = ~pb[c];
                while (nb) {               // wave-uniform, ~0.5 iters/row avg
                    const int k = __ffsll(nb) - 1;
                    nb &= nb - 1;
                    const float dk = __shfl(dv[c], k);
#pragma unroll
                    for (int c2 = 0; c2 < 8; c2++) {
                        if ((pb[c2] >> lane) & 1ull) {   // lane's j is positive
                            const float v = dv[c2] - dk;
                            sum += fmaxf(v, 0.0f);
                            cnt += (v > 1e-16f) ? 1u : 0u;
                        }
                    }
                }
            }
#pragma unroll
            for (int off = 32; off > 0; off >>= 1) {
                sum += __shfl_down(sum, off);
                cnt += __shfl_down(cnt, off);
            }
        }
    }

    // ---- unconditional slot write (thread 0 holds reduced or zero values) ---
    if (t == 0) {
        slots[2 * i]                  = sum;
        ((unsigned*)slots)[2 * i + 1] = cnt;
    }
}

// ---------------- finalize: reduce 512 slots, divide -------------------------
__global__ __launch_bounds__(256) void finalize_kernel(
    const float* __restrict__ slots, float* __restrict__ out)
{
    __shared__ float    wsum[4];
    __shared__ unsigned wcnt[4];
    const int t    = threadIdx.x;          // 256
    const int lane = t & 63;
    const int w    = t >> 6;

    float s = 0.f; unsigned c = 0u;
    for (int b = t; b < NB; b += 256) {
        s += slots[2 * b];
        c += ((const unsigned*)slots)[2 * b + 1];
    }
#pragma unroll
    for (int off = 32; off > 0; off >>= 1) {
        s += __shfl_down(s, off);
        c += __shfl_down(c, off);
    }
    if (lane == 0) { wsum[w] = s; wcnt[w] = c; }
    __syncthreads();
    if (t == 0) {
        s = wsum[0] + wsum[1] + wsum[2] + wsum[3];
        c = wcnt[0] + wcnt[1] + wcnt[2] + wcnt[3];
        out[0] = s / ((float)c + 1e-16f);
    }
}

extern "C" void kernel_launch(void* const* d_in, const int* in_sizes, int n_in,
                              void* d_out, int out_size, void* d_ws, size_t ws_size,
                              hipStream_t stream) {
    const float* src    = (const float*)d_in[0];
    const int*   labels = (const int*)d_in[1];
    float* slots = (float*)d_ws;

    hipLaunchKernelGGL(row_kernel,      dim3(NB), dim3(NT),  0, stream, src, labels, slots);
    hipLaunchKernelGGL(finalize_kernel, dim3(1),  dim3(256), 0, stream, slots, (float*)d_out);
}